// Round 1
// baseline (1646.146 us; speedup 1.0000x reference)
//
#include <hip/hip_runtime.h>

#define NB      16
#define NPTS    4096
#define NPOINT  1024
#define NSAMPLE 32

// ---------------------------------------------------------------------------
// FPS: one block per batch, 512 threads x 8 points. Per iteration:
//   update mind, local argmax -> packed u64 key (valbits<<32)|~idx,
//   wave butterfly max, cross-wave via double-buffered LDS (1 barrier/iter).
// Exact IEEE f32 (no fma contraction) so argmax matches numpy bitwise.
// Writes new_xyz directly (cen coords are exact copies of xyz).
// ---------------------------------------------------------------------------
__global__ __launch_bounds__(512) void fps_kernel(const float* __restrict__ xyz,
                                                  float* __restrict__ out_xyz) {
  __shared__ float l[NPTS * 3];
  __shared__ unsigned long long red[2][8];
  const int b = blockIdx.x;
  const int t = threadIdx.x;
  const float* g = xyz + (size_t)b * NPTS * 3;
  {
    const float4* g4 = (const float4*)g;
    float4* l4 = (float4*)l;
#pragma unroll
    for (int m = 0; m < 6; ++m) l4[t + 512 * m] = g4[t + 512 * m];
  }
  __syncthreads();
  float px[8], py[8], pz[8], mind[8];
#pragma unroll
  for (int i = 0; i < 8; ++i) {
    const int j = t + 512 * i;
    px[i] = l[3 * j]; py[i] = l[3 * j + 1]; pz[i] = l[3 * j + 2];
    mind[i] = 1e10f;
  }
  int far = 0;
  float* ob = out_xyz + (size_t)b * NPOINT * 3;
  for (int it = 0; it < NPOINT; ++it) {
    const float cx = l[3 * far], cy = l[3 * far + 1], cz = l[3 * far + 2];
    if (t == 0) { ob[3 * it] = cx; ob[3 * it + 1] = cy; ob[3 * it + 2] = cz; }
    float bestv = -1.0f; int besti = 0;
#pragma unroll
    for (int i = 0; i < 8; ++i) {
      const float dx = __fsub_rn(px[i], cx);
      const float dy = __fsub_rn(py[i], cy);
      const float dz = __fsub_rn(pz[i], cz);
      const float d2 = __fadd_rn(__fadd_rn(__fmul_rn(dx, dx), __fmul_rn(dy, dy)),
                                 __fmul_rn(dz, dz));
      const float m = fminf(mind[i], d2);
      mind[i] = m;
      if (m > bestv) { bestv = m; besti = t + 512 * i; }  // ascending i => smallest idx on tie
    }
    unsigned long long key =
        ((unsigned long long)__float_as_uint(bestv) << 32) | (unsigned int)(~besti);
#pragma unroll
    for (int msk = 1; msk < 64; msk <<= 1) {
      const unsigned long long o = __shfl_xor(key, msk, 64);
      if (o > key) key = o;
    }
    const int buf = it & 1;
    if ((t & 63) == 0) red[buf][t >> 6] = key;
    __syncthreads();
    unsigned long long kmax = red[buf][0];
#pragma unroll
    for (int w = 1; w < 8; ++w) {
      const unsigned long long r = red[buf][w];
      if (r > kmax) kmax = r;
    }
    far = (int)(~(unsigned int)kmax);
  }
}

// ---------------------------------------------------------------------------
// Ball query: first NSAMPLE ascending in-radius indices per query (== the
// reference's sort-then-take), early exit, pad with first hit.
// 256 blocks x 64 threads; batch xyz in LDS (broadcast reads, uniform j).
// Writes int idx to ws and float idx to d_out.
// ---------------------------------------------------------------------------
__global__ __launch_bounds__(64) void ballq_kernel(const float* __restrict__ xyz,
                                                   const float* __restrict__ new_xyz,
                                                   int* __restrict__ ballidx,
                                                   float* __restrict__ out_idx) {
  __shared__ float l[NPTS * 3];
  const int b = blockIdx.x >> 4;
  const int s = ((blockIdx.x & 15) << 6) + threadIdx.x;
  const float* g = xyz + (size_t)b * NPTS * 3;
  {
    const float4* g4 = (const float4*)g;
    float4* l4 = (float4*)l;
#pragma unroll
    for (int m = 0; m < 48; ++m) l4[threadIdx.x + 64 * m] = g4[threadIdx.x + 64 * m];
  }
  __syncthreads();
  const size_t q = (size_t)b * NPOINT + s;
  const float nx = new_xyz[q * 3], ny = new_xyz[q * 3 + 1], nz = new_xyz[q * 3 + 2];
  const float r2 = (float)(0.2 * 0.2);  // double->f32, NOT 0.2f*0.2f (1 ulp off)
  int cnt = 0, first = 0;
  int* oi = ballidx + q * NSAMPLE;
  float* of = out_idx + q * NSAMPLE;
  for (int j = 0; j < NPTS; ++j) {
    const float dx = __fsub_rn(l[3 * j], nx);
    const float dy = __fsub_rn(l[3 * j + 1], ny);
    const float dz = __fsub_rn(l[3 * j + 2], nz);
    const float d2 = __fadd_rn(__fadd_rn(__fmul_rn(dx, dx), __fmul_rn(dy, dy)),
                               __fmul_rn(dz, dz));
    if (d2 <= r2) {
      if (cnt == 0) first = j;
      oi[cnt] = j;
      of[cnt] = (float)j;
      if (++cnt == NSAMPLE) break;
    }
  }
  for (int m = cnt; m < NSAMPLE; ++m) { oi[m] = first; of[m] = (float)first; }
}

// ---------------------------------------------------------------------------
// P1[b,j,d] = sum_c points[b,j,c] * W0[3+c, d]  (points-part of layer 1,
// depends only on the original point -> computed once: 0.5 GF not 4.4 GF).
// ---------------------------------------------------------------------------
__global__ __launch_bounds__(256) void p1_kernel(const float* __restrict__ pts,
                                                 const float* __restrict__ W0,
                                                 float* __restrict__ P1) {
  __shared__ float sw[4096];
  const int t = threadIdx.x;
  {
    const float4* w4 = (const float4*)(W0 + 192);
    float4* s4 = (float4*)sw;
#pragma unroll
    for (int m = 0; m < 4; ++m) s4[t + 256 * m] = w4[t + 256 * m];
  }
  __syncthreads();
  const size_t r = (size_t)blockIdx.x * 256 + t;
  const float* prow = pts + r * 64;
  float acc[64];
#pragma unroll
  for (int d = 0; d < 64; ++d) acc[d] = 0.0f;
#pragma unroll
  for (int cq = 0; cq < 16; ++cq) {
    const float4 p4 = *(const float4*)(prow + cq * 4);
    const float pv[4] = {p4.x, p4.y, p4.z, p4.w};
#pragma unroll
    for (int u = 0; u < 4; ++u) {
      const int c = cq * 4 + u;
#pragma unroll
      for (int d4 = 0; d4 < 16; ++d4) {
        const float4 w = *(const float4*)(&sw[c * 64 + d4 * 4]);
        acc[d4 * 4 + 0] = fmaf(pv[u], w.x, acc[d4 * 4 + 0]);
        acc[d4 * 4 + 1] = fmaf(pv[u], w.y, acc[d4 * 4 + 1]);
        acc[d4 * 4 + 2] = fmaf(pv[u], w.z, acc[d4 * 4 + 2]);
        acc[d4 * 4 + 3] = fmaf(pv[u], w.w, acc[d4 * 4 + 3]);
      }
    }
  }
  float* o = P1 + r * 64;
#pragma unroll
  for (int d4 = 0; d4 < 16; ++d4)
    *(float4*)(o + d4 * 4) =
        make_float4(acc[d4 * 4], acc[d4 * 4 + 1], acc[d4 * 4 + 2], acc[d4 * 4 + 3]);
}

// ---------------------------------------------------------------------------
// Fused group + MLP + maxpool. Thread = (query q, sample k); lanes 0..31 of a
// wave share q. h1/h2 in registers (static indices), weights in LDS
// (broadcast ds_read_b128). Layer 3 in 4 chunks of 32 cols; max over k via
// 5-step __shfl_xor within the 32-lane group; lane k==0 stores.
// ---------------------------------------------------------------------------
__global__ __launch_bounds__(256) void mlp_kernel(
    const float* __restrict__ xyz, const float* __restrict__ new_xyz,
    const int* __restrict__ ballidx, const float* __restrict__ P1,
    const float* __restrict__ W0, const float* __restrict__ b0,
    const float* __restrict__ W1, const float* __restrict__ b1,
    const float* __restrict__ W2, const float* __restrict__ b2,
    float* __restrict__ out_np) {
  __shared__ float sW1[4096];
  __shared__ float sW2[8192];
  __shared__ float sW0[192];
  __shared__ float sb0[64], sb1[64], sb2[128];
  const int t = threadIdx.x;
  for (int j = t; j < 4096; j += 256) sW1[j] = W1[j];
  for (int j = t; j < 8192; j += 256) sW2[j] = W2[j];
  if (t < 192) sW0[t] = W0[t];
  if (t < 64) { sb0[t] = b0[t]; sb1[t] = b1[t]; }
  if (t < 128) sb2[t] = b2[t];
  __syncthreads();

  const int item = blockIdx.x * 256 + t;
  const int k = item & 31;
  const int q = item >> 5;
  const int b = q >> 10;
  const int idx = ballidx[(size_t)q * 32 + k];
  const float nx = new_xyz[(size_t)q * 3];
  const float ny = new_xyz[(size_t)q * 3 + 1];
  const float nz = new_xyz[(size_t)q * 3 + 2];
  const float* p = xyz + ((size_t)b * NPTS + idx) * 3;
  const float dx = p[0] - nx, dy = p[1] - ny, dz = p[2] - nz;

  // layer 1: h1 = relu(P1[idx] + dxyz . W0[0:3] + b0)
  float h1[64];
  const float* p1r = P1 + ((size_t)b * NPTS + idx) * 64;
#pragma unroll
  for (int d4 = 0; d4 < 16; ++d4) {
    const float4 pv = *(const float4*)(p1r + d4 * 4);
    const float pe[4] = {pv.x, pv.y, pv.z, pv.w};
#pragma unroll
    for (int u = 0; u < 4; ++u) {
      const int d = d4 * 4 + u;
      const float v = pe[u] + dx * sW0[d] + dy * sW0[64 + d] + dz * sW0[128 + d] + sb0[d];
      h1[d] = fmaxf(v, 0.0f);
    }
  }

  // layer 2
  float h2[64];
#pragma unroll
  for (int j4 = 0; j4 < 16; ++j4) {
    const float4 bb = *(const float4*)(&sb1[j4 * 4]);
    h2[j4 * 4 + 0] = bb.x; h2[j4 * 4 + 1] = bb.y;
    h2[j4 * 4 + 2] = bb.z; h2[j4 * 4 + 3] = bb.w;
  }
#pragma unroll
  for (int c = 0; c < 64; ++c) {
    const float hc = h1[c];
#pragma unroll
    for (int j4 = 0; j4 < 16; ++j4) {
      const float4 w = *(const float4*)(&sW1[c * 64 + j4 * 4]);
      h2[j4 * 4 + 0] = fmaf(hc, w.x, h2[j4 * 4 + 0]);
      h2[j4 * 4 + 1] = fmaf(hc, w.y, h2[j4 * 4 + 1]);
      h2[j4 * 4 + 2] = fmaf(hc, w.z, h2[j4 * 4 + 2]);
      h2[j4 * 4 + 3] = fmaf(hc, w.w, h2[j4 * 4 + 3]);
    }
  }
#pragma unroll
  for (int j = 0; j < 64; ++j) h2[j] = fmaxf(h2[j], 0.0f);

  // layer 3 in 4 chunks of 32 cols + k-max reduce + store
  float* outq = out_np + (size_t)q * 128;
  for (int jb = 0; jb < 4; ++jb) {
    float acc[32];
#pragma unroll
    for (int j8 = 0; j8 < 8; ++j8) {
      const float4 bb = *(const float4*)(&sb2[jb * 32 + j8 * 4]);
      acc[j8 * 4 + 0] = bb.x; acc[j8 * 4 + 1] = bb.y;
      acc[j8 * 4 + 2] = bb.z; acc[j8 * 4 + 3] = bb.w;
    }
#pragma unroll
    for (int c = 0; c < 64; ++c) {
      const float hc = h2[c];
#pragma unroll
      for (int j8 = 0; j8 < 8; ++j8) {
        const float4 w = *(const float4*)(&sW2[c * 128 + jb * 32 + j8 * 4]);
        acc[j8 * 4 + 0] = fmaf(hc, w.x, acc[j8 * 4 + 0]);
        acc[j8 * 4 + 1] = fmaf(hc, w.y, acc[j8 * 4 + 1]);
        acc[j8 * 4 + 2] = fmaf(hc, w.z, acc[j8 * 4 + 2]);
        acc[j8 * 4 + 3] = fmaf(hc, w.w, acc[j8 * 4 + 3]);
      }
    }
#pragma unroll
    for (int j = 0; j < 32; ++j) acc[j] = fmaxf(acc[j], 0.0f);
#pragma unroll
    for (int msk = 16; msk >= 1; msk >>= 1) {
#pragma unroll
      for (int j = 0; j < 32; ++j) acc[j] = fmaxf(acc[j], __shfl_xor(acc[j], msk, 64));
    }
    if (k == 0) {
#pragma unroll
      for (int j8 = 0; j8 < 8; ++j8)
        *(float4*)(outq + jb * 32 + j8 * 4) =
            make_float4(acc[j8 * 4 + 0], acc[j8 * 4 + 1], acc[j8 * 4 + 2], acc[j8 * 4 + 3]);
    }
  }
}

extern "C" void kernel_launch(void* const* d_in, const int* in_sizes, int n_in,
                              void* d_out, int out_size, void* d_ws, size_t ws_size,
                              hipStream_t stream) {
  const float* xyz = (const float*)d_in[0];
  const float* pts = (const float*)d_in[1];
  const float* W0  = (const float*)d_in[2];
  const float* b0  = (const float*)d_in[3];
  const float* W1  = (const float*)d_in[4];
  const float* b1  = (const float*)d_in[5];
  const float* W2  = (const float*)d_in[6];
  const float* b2  = (const float*)d_in[7];

  float* out      = (float*)d_out;
  float* out_xyz  = out;                       // [16,1024,3]
  float* out_np   = out + 16 * 1024 * 3;       // [16,1024,128]
  float* out_idx  = out_np + 16 * 1024 * 128;  // [16,1024,32] as float values

  int*   ballidx = (int*)d_ws;                               // 2 MB
  float* P1      = (float*)((char*)d_ws + (2u << 20));       // 16 MB

  fps_kernel<<<NB, 512, 0, stream>>>(xyz, out_xyz);
  p1_kernel<<<256, 256, 0, stream>>>(pts, W0, P1);
  ballq_kernel<<<256, 64, 0, stream>>>(xyz, out_xyz, ballidx, out_idx);
  mlp_kernel<<<2048, 256, 0, stream>>>(xyz, out_xyz, ballidx, P1,
                                       W0, b0, W1, b1, W2, b2, out_np);
}

// Round 2
// 1340.752 us; speedup vs baseline: 1.2278x; 1.2278x over previous
//
#include <hip/hip_runtime.h>

#define NB      16
#define NPTS    4096
#define NPOINT  1024
#define NSAMPLE 32

// ---------------- DPP helpers (exact u64-key max butterflies) ----------------
template <int C>
__device__ __forceinline__ int dppi(int v) {
  return __builtin_amdgcn_update_dpp(0, v, C, 0xf, 0xf, true);
}

template <int C>
__device__ __forceinline__ unsigned long long dppmax_u64(unsigned long long k) {
  int lo = dppi<C>((int)(unsigned)k);
  int hi = dppi<C>((int)(k >> 32));
  unsigned long long o = ((unsigned long long)(unsigned)hi << 32) | (unsigned)lo;
  return o > k ? o : k;
}

__device__ __forceinline__ unsigned long long swzmax16_u64(unsigned long long k) {
  int lo = __builtin_amdgcn_ds_swizzle((int)(unsigned)k, 0x401F);  // lane ^= 16
  int hi = __builtin_amdgcn_ds_swizzle((int)(k >> 32), 0x401F);
  unsigned long long o = ((unsigned long long)(unsigned)hi << 32) | (unsigned)lo;
  return o > k ? o : k;
}

template <int C>
__device__ __forceinline__ void redstep(unsigned long long& k, float& x, float& y, float& z) {
  int lo = dppi<C>((int)(unsigned)k);
  int hi = dppi<C>((int)(k >> 32));
  int ox = dppi<C>(__float_as_int(x));
  int oy = dppi<C>(__float_as_int(y));
  int oz = dppi<C>(__float_as_int(z));
  unsigned long long o = ((unsigned long long)(unsigned)hi << 32) | (unsigned)lo;
  bool c = o > k;
  k = c ? o : k;
  x = c ? __int_as_float(ox) : x;
  y = c ? __int_as_float(oy) : y;
  z = c ? __int_as_float(oz) : z;
}

// ---------------------------------------------------------------------------
// FPS v2: 1 block/batch, 256 threads (1 wave/SIMD), 16 points/thread.
// Per iter: exact-IEEE mind update -> in-reg u64-key tree (16->1) ->
// DPP butterfly within 32-lane group (xor 1,2,4(via x7),8(via x15),16) ->
// owner lane writes {key, coords} tuple to LDS (double-buffered) ->
// ONE barrier -> every lane loads partial (lane&7), 3-step DPP tuple reduce
// -> center coords in-register for next iter. No LDS center re-read, no
// ds-based shuffles except the single xor16 swizzle.
// ---------------------------------------------------------------------------
__global__ __launch_bounds__(256) void fps_kernel(const float* __restrict__ xyz,
                                                  float* __restrict__ out_xyz) {
  __shared__ unsigned long long skey[2][8];
  __shared__ float4 scoord[2][8];
  const int b = blockIdx.x, t = threadIdx.x;
  const int lane = t & 63;
  const int grp = t >> 5;  // 8 groups of 32 lanes
  const float* g = xyz + (size_t)b * NPTS * 3;
  float px[16], py[16], pz[16], mind[16];
  unsigned int nlo[16];
#pragma unroll
  for (int i = 0; i < 16; ++i) {
    const int j = t + 256 * i;
    px[i] = g[3 * j]; py[i] = g[3 * j + 1]; pz[i] = g[3 * j + 2];
    mind[i] = 1e10f;
    nlo[i] = ~(unsigned)j;
  }
  float cx = g[0], cy = g[1], cz = g[2];  // far = 0 initially
  float* ob = out_xyz + (size_t)b * NPOINT * 3;
  for (int it = 0; it < NPOINT; ++it) {
    if (t == 0) { ob[3 * it] = cx; ob[3 * it + 1] = cy; ob[3 * it + 2] = cz; }
    unsigned long long k[16];
#pragma unroll
    for (int i = 0; i < 16; ++i) {
      const float dx = __fsub_rn(px[i], cx);
      const float dy = __fsub_rn(py[i], cy);
      const float dz = __fsub_rn(pz[i], cz);
      const float d2 = __fadd_rn(__fadd_rn(__fmul_rn(dx, dx), __fmul_rn(dy, dy)),
                                 __fmul_rn(dz, dz));
      const float m = fminf(mind[i], d2);
      mind[i] = m;
      k[i] = ((unsigned long long)__float_as_uint(m) << 32) | nlo[i];  // keys unique
    }
#pragma unroll
    for (int s = 8; s; s >>= 1)
#pragma unroll
      for (int i = 0; i < s; ++i) k[i] = k[i] > k[i + s] ? k[i] : k[i + s];
    unsigned long long kk = k[0];
    kk = dppmax_u64<0xB1>(kk);   // xor 1
    kk = dppmax_u64<0x4E>(kk);   // xor 2
    kk = dppmax_u64<0x141>(kk);  // half-mirror == xor 4 at quad granularity
    kk = dppmax_u64<0x140>(kk);  // mirror == xor 8 at 8-lane granularity
    kk = swzmax16_u64(kk);       // xor 16 -> 32-lane group max
    const unsigned int idx = ~(unsigned)kk;  // winning point index (group-uniform)
    const int buf = it & 1;
    if ((int)(idx & 255) == t) {  // exactly one owner lane per 32-lane group
      const int iw = idx >> 8;
      float ox = px[0], oy = py[0], oz = pz[0];
#pragma unroll
      for (int i = 1; i < 16; ++i) {
        const bool c = (iw == i);
        ox = c ? px[i] : ox; oy = c ? py[i] : oy; oz = c ? pz[i] : oz;
      }
      skey[buf][grp] = kk;
      scoord[buf][grp] = make_float4(ox, oy, oz, 0.0f);
    }
    __syncthreads();
    unsigned long long rk = skey[buf][lane & 7];
    const float4 rc = scoord[buf][lane & 7];
    float rx = rc.x, ry = rc.y, rz = rc.z;
    redstep<0xB1>(rk, rx, ry, rz);   // xor 1
    redstep<0x4E>(rk, rx, ry, rz);   // xor 2
    redstep<0x141>(rk, rx, ry, rz);  // xor 7 -> completes 8-partial coverage
    cx = rx; cy = ry; cz = rz;
  }
}

// ---------------------------------------------------------------------------
// Ball query v2: one wave per query; 64 candidate points per step; ordered
// append via __ballot + prefix popcount; uniform early exit at 32 hits.
// Exact same d2 arithmetic/constant as the reference.
// ---------------------------------------------------------------------------
__global__ __launch_bounds__(256) void ballq_kernel(const float* __restrict__ xyz,
                                                    const float* __restrict__ new_xyz,
                                                    int* __restrict__ ballidx,
                                                    float* __restrict__ out_idx) {
  __shared__ int sidx[4][NSAMPLE];
  const int wv = threadIdx.x >> 6, lane = threadIdx.x & 63;
  const int q = blockIdx.x * 4 + wv;  // 4096 blocks x 4 queries
  const int b = q >> 10;
  const float* g = xyz + (size_t)b * NPTS * 3;
  const float nx = new_xyz[(size_t)q * 3];
  const float ny = new_xyz[(size_t)q * 3 + 1];
  const float nz = new_xyz[(size_t)q * 3 + 2];
  const float r2 = (float)(0.2 * 0.2);  // double->f32 (NOT 0.2f*0.2f)
  int cnt = 0;
  for (int base = 0; base < NPTS; base += 64) {
    const int j = base + lane;
    const float dx = __fsub_rn(g[3 * j], nx);
    const float dy = __fsub_rn(g[3 * j + 1], ny);
    const float dz = __fsub_rn(g[3 * j + 2], nz);
    const float d2 = __fadd_rn(__fadd_rn(__fmul_rn(dx, dx), __fmul_rn(dy, dy)),
                               __fmul_rn(dz, dz));
    const bool hit = d2 <= r2;
    const unsigned long long m = __ballot(hit);
    const int pos = cnt + __popcll(m & ((1ull << lane) - 1ull));
    if (hit && pos < NSAMPLE) sidx[wv][pos] = j;
    cnt += __popcll(m);
    if (cnt >= NSAMPLE) break;  // wave-uniform
  }
  __syncthreads();
  const int capped = cnt < NSAMPLE ? cnt : NSAMPLE;
  if (lane < NSAMPLE) {
    const int v = sidx[wv][lane < capped ? lane : 0];  // pad with first hit
    ballidx[(size_t)q * NSAMPLE + lane] = v;
    out_idx[(size_t)q * NSAMPLE + lane] = (float)v;
  }
}

// ---------------------------------------------------------------------------
// P1[b,j,d] = sum_c points[b,j,c] * W0[3+c, d]  (points-part of layer 1).
// ---------------------------------------------------------------------------
__global__ __launch_bounds__(256) void p1_kernel(const float* __restrict__ pts,
                                                 const float* __restrict__ W0,
                                                 float* __restrict__ P1) {
  __shared__ float sw[4096];
  const int t = threadIdx.x;
  {
    const float4* w4 = (const float4*)(W0 + 192);
    float4* s4 = (float4*)sw;
#pragma unroll
    for (int m = 0; m < 4; ++m) s4[t + 256 * m] = w4[t + 256 * m];
  }
  __syncthreads();
  const size_t r = (size_t)blockIdx.x * 256 + t;
  const float* prow = pts + r * 64;
  float acc[64];
#pragma unroll
  for (int d = 0; d < 64; ++d) acc[d] = 0.0f;
#pragma unroll
  for (int cq = 0; cq < 16; ++cq) {
    const float4 p4 = *(const float4*)(prow + cq * 4);
    const float pv[4] = {p4.x, p4.y, p4.z, p4.w};
#pragma unroll
    for (int u = 0; u < 4; ++u) {
      const int c = cq * 4 + u;
#pragma unroll
      for (int d4 = 0; d4 < 16; ++d4) {
        const float4 w = *(const float4*)(&sw[c * 64 + d4 * 4]);
        acc[d4 * 4 + 0] = fmaf(pv[u], w.x, acc[d4 * 4 + 0]);
        acc[d4 * 4 + 1] = fmaf(pv[u], w.y, acc[d4 * 4 + 1]);
        acc[d4 * 4 + 2] = fmaf(pv[u], w.z, acc[d4 * 4 + 2]);
        acc[d4 * 4 + 3] = fmaf(pv[u], w.w, acc[d4 * 4 + 3]);
      }
    }
  }
  float* o = P1 + r * 64;
#pragma unroll
  for (int d4 = 0; d4 < 16; ++d4)
    *(float4*)(o + d4 * 4) =
        make_float4(acc[d4 * 4], acc[d4 * 4 + 1], acc[d4 * 4 + 2], acc[d4 * 4 + 3]);
}

// ---------------------------------------------------------------------------
// Fused group + MLP + maxpool. Weights/biases read DIRECTLY from global with
// wave-uniform addresses (scalar-load path, L2-hot) -- no LDS pipe pressure.
// Thread = (query q, sample k); h1/h2 in registers; k-max via __shfl_xor.
// ---------------------------------------------------------------------------
__global__ __launch_bounds__(256) void mlp_kernel(
    const float* __restrict__ xyz, const float* __restrict__ new_xyz,
    const int* __restrict__ ballidx, const float* __restrict__ P1,
    const float* __restrict__ W0, const float* __restrict__ b0,
    const float* __restrict__ W1, const float* __restrict__ b1,
    const float* __restrict__ W2, const float* __restrict__ b2,
    float* __restrict__ out_np) {
  const int t = threadIdx.x;
  const int item = blockIdx.x * 256 + t;
  const int k = item & 31;
  const int q = item >> 5;
  const int b = q >> 10;
  const int idx = ballidx[(size_t)q * 32 + k];
  const float nx = new_xyz[(size_t)q * 3];
  const float ny = new_xyz[(size_t)q * 3 + 1];
  const float nz = new_xyz[(size_t)q * 3 + 2];
  const float* p = xyz + ((size_t)b * NPTS + idx) * 3;
  const float dx = p[0] - nx, dy = p[1] - ny, dz = p[2] - nz;

  // layer 1: h1 = relu(P1[idx] + dxyz . W0[0:3] + b0)
  float h1[64];
  const float* p1r = P1 + ((size_t)b * NPTS + idx) * 64;
#pragma unroll
  for (int d4 = 0; d4 < 16; ++d4) {
    const float4 pv = *(const float4*)(p1r + d4 * 4);
    const float pe[4] = {pv.x, pv.y, pv.z, pv.w};
#pragma unroll
    for (int u = 0; u < 4; ++u) {
      const int d = d4 * 4 + u;
      const float v = pe[u] + dx * W0[d] + dy * W0[64 + d] + dz * W0[128 + d] + b0[d];
      h1[d] = fmaxf(v, 0.0f);
    }
  }

  // layer 2
  float h2[64];
#pragma unroll
  for (int j4 = 0; j4 < 16; ++j4) {
    const float4 bb = *(const float4*)(&b1[j4 * 4]);
    h2[j4 * 4 + 0] = bb.x; h2[j4 * 4 + 1] = bb.y;
    h2[j4 * 4 + 2] = bb.z; h2[j4 * 4 + 3] = bb.w;
  }
#pragma unroll
  for (int c = 0; c < 64; ++c) {
    const float hc = h1[c];
#pragma unroll
    for (int j4 = 0; j4 < 16; ++j4) {
      const float4 w = *(const float4*)(&W1[c * 64 + j4 * 4]);
      h2[j4 * 4 + 0] = fmaf(hc, w.x, h2[j4 * 4 + 0]);
      h2[j4 * 4 + 1] = fmaf(hc, w.y, h2[j4 * 4 + 1]);
      h2[j4 * 4 + 2] = fmaf(hc, w.z, h2[j4 * 4 + 2]);
      h2[j4 * 4 + 3] = fmaf(hc, w.w, h2[j4 * 4 + 3]);
    }
  }
#pragma unroll
  for (int j = 0; j < 64; ++j) h2[j] = fmaxf(h2[j], 0.0f);

  // layer 3 in 4 chunks of 32 cols + k-max reduce + store
  float* outq = out_np + (size_t)q * 128;
  for (int jb = 0; jb < 4; ++jb) {
    float acc[32];
#pragma unroll
    for (int j8 = 0; j8 < 8; ++j8) {
      const float4 bb = *(const float4*)(&b2[jb * 32 + j8 * 4]);
      acc[j8 * 4 + 0] = bb.x; acc[j8 * 4 + 1] = bb.y;
      acc[j8 * 4 + 2] = bb.z; acc[j8 * 4 + 3] = bb.w;
    }
#pragma unroll
    for (int c = 0; c < 64; ++c) {
      const float hc = h2[c];
#pragma unroll
      for (int j8 = 0; j8 < 8; ++j8) {
        const float4 w = *(const float4*)(&W2[c * 128 + jb * 32 + j8 * 4]);
        acc[j8 * 4 + 0] = fmaf(hc, w.x, acc[j8 * 4 + 0]);
        acc[j8 * 4 + 1] = fmaf(hc, w.y, acc[j8 * 4 + 1]);
        acc[j8 * 4 + 2] = fmaf(hc, w.z, acc[j8 * 4 + 2]);
        acc[j8 * 4 + 3] = fmaf(hc, w.w, acc[j8 * 4 + 3]);
      }
    }
#pragma unroll
    for (int j = 0; j < 32; ++j) acc[j] = fmaxf(acc[j], 0.0f);
#pragma unroll
    for (int msk = 16; msk >= 1; msk >>= 1) {
#pragma unroll
      for (int j = 0; j < 32; ++j) acc[j] = fmaxf(acc[j], __shfl_xor(acc[j], msk, 64));
    }
    if (k == 0) {
#pragma unroll
      for (int j8 = 0; j8 < 8; ++j8)
        *(float4*)(outq + jb * 32 + j8 * 4) =
            make_float4(acc[j8 * 4 + 0], acc[j8 * 4 + 1], acc[j8 * 4 + 2], acc[j8 * 4 + 3]);
    }
  }
}

extern "C" void kernel_launch(void* const* d_in, const int* in_sizes, int n_in,
                              void* d_out, int out_size, void* d_ws, size_t ws_size,
                              hipStream_t stream) {
  const float* xyz = (const float*)d_in[0];
  const float* pts = (const float*)d_in[1];
  const float* W0  = (const float*)d_in[2];
  const float* b0  = (const float*)d_in[3];
  const float* W1  = (const float*)d_in[4];
  const float* b1  = (const float*)d_in[5];
  const float* W2  = (const float*)d_in[6];
  const float* b2  = (const float*)d_in[7];

  float* out      = (float*)d_out;
  float* out_xyz  = out;                       // [16,1024,3]
  float* out_np   = out + 16 * 1024 * 3;       // [16,1024,128]
  float* out_idx  = out_np + 16 * 1024 * 128;  // [16,1024,32] as float values

  int*   ballidx = (int*)d_ws;                               // 2 MB
  float* P1      = (float*)((char*)d_ws + (2u << 20));       // 16 MB

  fps_kernel<<<NB, 256, 0, stream>>>(xyz, out_xyz);
  p1_kernel<<<256, 256, 0, stream>>>(pts, W0, P1);
  ballq_kernel<<<4096, 256, 0, stream>>>(xyz, out_xyz, ballidx, out_idx);
  mlp_kernel<<<2048, 256, 0, stream>>>(xyz, out_xyz, ballidx, P1,
                                       W0, b0, W1, b1, W2, b2, out_np);
}

// Round 3
// 1005.202 us; speedup vs baseline: 1.6376x; 1.3338x over previous
//
#include <hip/hip_runtime.h>

#define NB      16
#define NPTS    4096
#define NPOINT  1024
#define NSAMPLE 32

// ---------------- DPP / swizzle / bpermute u64-key max helpers ----------------
template <int C>
__device__ __forceinline__ int dppi(int v) {
  return __builtin_amdgcn_update_dpp(0, v, C, 0xf, 0xf, true);
}

template <int C>
__device__ __forceinline__ unsigned long long dppmax_u64(unsigned long long k) {
  int lo = dppi<C>((int)(unsigned)k);
  int hi = dppi<C>((int)(k >> 32));
  unsigned long long o = ((unsigned long long)(unsigned)hi << 32) | (unsigned)lo;
  return o > k ? o : k;
}

__device__ __forceinline__ unsigned long long swzmax16_u64(unsigned long long k) {
  int lo = __builtin_amdgcn_ds_swizzle((int)(unsigned)k, 0x401F);  // lane ^= 16
  int hi = __builtin_amdgcn_ds_swizzle((int)(k >> 32), 0x401F);
  unsigned long long o = ((unsigned long long)(unsigned)hi << 32) | (unsigned)lo;
  return o > k ? o : k;
}

__device__ __forceinline__ unsigned long long bpermmax32_u64(unsigned long long k, int addr) {
  int lo = __builtin_amdgcn_ds_bpermute(addr, (int)(unsigned)k);  // lane ^= 32
  int hi = __builtin_amdgcn_ds_bpermute(addr, (int)(k >> 32));
  unsigned long long o = ((unsigned long long)(unsigned)hi << 32) | (unsigned)lo;
  return o > k ? o : k;
}

// ---------------------------------------------------------------------------
// FPS v3: 1 block/batch, 512 threads (8 waves = 2/SIMD for latency hiding),
// 8 points/thread (strided j = t + 512*i). Per iter:
//   exact-IEEE mind update + incremental f32 argmax (smallest-j ties exact),
//   pack ONE u64 key, 6-step in-wave butterfly (4 DPP + swizzle^16 + bperm^32),
//   wave lane0 writes 1 partial -> ONE barrier -> 3-step DPP final over 8
//   partials -> winner idx uniform -> center coords via 3 broadcast LDS reads.
// No owner-lane branch, no coord-carrying reduce, double-buffered partials.
// ---------------------------------------------------------------------------
__global__ __launch_bounds__(512) void fps_kernel(const float* __restrict__ xyz,
                                                  float* __restrict__ out_xyz) {
  __shared__ float lx[NPTS], ly[NPTS], lz[NPTS];
  __shared__ unsigned long long part[2][8];
  const int b = blockIdx.x, t = threadIdx.x;
  const int lane = t & 63;
  const float* g = xyz + (size_t)b * NPTS * 3;
  for (int j = t; j < NPTS; j += 512) {
    lx[j] = g[3 * j]; ly[j] = g[3 * j + 1]; lz[j] = g[3 * j + 2];
  }
  __syncthreads();
  float px[8], py[8], pz[8], mind[8];
#pragma unroll
  for (int i = 0; i < 8; ++i) {
    const int j = t + 512 * i;
    px[i] = lx[j]; py[i] = ly[j]; pz[i] = lz[j];
    mind[i] = 1e10f;
  }
  const int baddr = ((lane ^ 32) & 63) << 2;  // bpermute byte addr, loop-invariant
  float cx = lx[0], cy = ly[0], cz = lz[0];   // far = 0 initially
  float* ob = out_xyz + (size_t)b * NPOINT * 3;
  for (int it = 0; it < NPOINT; ++it) {
    if (t == 0) { ob[3 * it] = cx; ob[3 * it + 1] = cy; ob[3 * it + 2] = cz; }
    float vmax = -1.0f;
    unsigned aj = 0;
#pragma unroll
    for (int i = 0; i < 8; ++i) {
      const float dx = __fsub_rn(px[i], cx);
      const float dy = __fsub_rn(py[i], cy);
      const float dz = __fsub_rn(pz[i], cz);
      const float d2 = __fadd_rn(__fadd_rn(__fmul_rn(dx, dx), __fmul_rn(dy, dy)),
                                 __fmul_rn(dz, dz));
      const float m = fminf(mind[i], d2);
      mind[i] = m;
      if (m > vmax) { vmax = m; aj = (unsigned)(t + 512 * i); }  // strict > keeps smallest j
    }
    unsigned long long key =
        ((unsigned long long)__float_as_uint(vmax) << 32) | (unsigned)(~aj);
    key = dppmax_u64<0xB1>(key);    // xor 1
    key = dppmax_u64<0x4E>(key);    // xor 2
    key = dppmax_u64<0x141>(key);   // half-mirror (xor 7 in 8)
    key = dppmax_u64<0x140>(key);   // mirror (xor 15 in 16)
    key = swzmax16_u64(key);        // xor 16
    key = bpermmax32_u64(key, baddr);  // xor 32 -> full-wave max
    const int buf = it & 1;
    if (lane == 0) part[buf][t >> 6] = key;
    __syncthreads();
    unsigned long long rk = part[buf][lane & 7];
    rk = dppmax_u64<0xB1>(rk);    // xor 1
    rk = dppmax_u64<0x4E>(rk);    // xor 2
    rk = dppmax_u64<0x141>(rk);   // xor 7 -> covers all 8 partials
    const unsigned idx = ~(unsigned)rk;  // winner point index (block-uniform)
    cx = lx[idx]; cy = ly[idx]; cz = lz[idx];  // broadcast LDS reads
  }
}

// ---------------------------------------------------------------------------
// Ball query: one wave per query; 64 candidates/step; ordered append via
// __ballot + prefix popcount; uniform early exit at 32 hits.
// ---------------------------------------------------------------------------
__global__ __launch_bounds__(256) void ballq_kernel(const float* __restrict__ xyz,
                                                    const float* __restrict__ new_xyz,
                                                    int* __restrict__ ballidx,
                                                    float* __restrict__ out_idx) {
  __shared__ int sidx[4][NSAMPLE];
  const int wv = threadIdx.x >> 6, lane = threadIdx.x & 63;
  const int q = blockIdx.x * 4 + wv;
  const int b = q >> 10;
  const float* g = xyz + (size_t)b * NPTS * 3;
  const float nx = new_xyz[(size_t)q * 3];
  const float ny = new_xyz[(size_t)q * 3 + 1];
  const float nz = new_xyz[(size_t)q * 3 + 2];
  const float r2 = (float)(0.2 * 0.2);  // double->f32 (NOT 0.2f*0.2f)
  int cnt = 0;
  for (int base = 0; base < NPTS; base += 64) {
    const int j = base + lane;
    const float dx = __fsub_rn(g[3 * j], nx);
    const float dy = __fsub_rn(g[3 * j + 1], ny);
    const float dz = __fsub_rn(g[3 * j + 2], nz);
    const float d2 = __fadd_rn(__fadd_rn(__fmul_rn(dx, dx), __fmul_rn(dy, dy)),
                               __fmul_rn(dz, dz));
    const bool hit = d2 <= r2;
    const unsigned long long m = __ballot(hit);
    const int pos = cnt + __popcll(m & ((1ull << lane) - 1ull));
    if (hit && pos < NSAMPLE) sidx[wv][pos] = j;
    cnt += __popcll(m);
    if (cnt >= NSAMPLE) break;  // wave-uniform
  }
  __syncthreads();
  const int capped = cnt < NSAMPLE ? cnt : NSAMPLE;
  if (lane < NSAMPLE) {
    const int v = sidx[wv][lane < capped ? lane : 0];  // pad with first hit
    ballidx[(size_t)q * NSAMPLE + lane] = v;
    out_idx[(size_t)q * NSAMPLE + lane] = (float)v;
  }
}

// ---------------------------------------------------------------------------
// P1[b,j,d] = sum_c points[b,j,c] * W0[3+c, d]  (points-part of layer 1).
// ---------------------------------------------------------------------------
__global__ __launch_bounds__(256) void p1_kernel(const float* __restrict__ pts,
                                                 const float* __restrict__ W0,
                                                 float* __restrict__ P1) {
  __shared__ float sw[4096];
  const int t = threadIdx.x;
  {
    const float4* w4 = (const float4*)(W0 + 192);
    float4* s4 = (float4*)sw;
#pragma unroll
    for (int m = 0; m < 4; ++m) s4[t + 256 * m] = w4[t + 256 * m];
  }
  __syncthreads();
  const size_t r = (size_t)blockIdx.x * 256 + t;
  const float* prow = pts + r * 64;
  float acc[64];
#pragma unroll
  for (int d = 0; d < 64; ++d) acc[d] = 0.0f;
#pragma unroll
  for (int cq = 0; cq < 16; ++cq) {
    const float4 p4 = *(const float4*)(prow + cq * 4);
    const float pv[4] = {p4.x, p4.y, p4.z, p4.w};
#pragma unroll
    for (int u = 0; u < 4; ++u) {
      const int c = cq * 4 + u;
#pragma unroll
      for (int d4 = 0; d4 < 16; ++d4) {
        const float4 w = *(const float4*)(&sw[c * 64 + d4 * 4]);
        acc[d4 * 4 + 0] = fmaf(pv[u], w.x, acc[d4 * 4 + 0]);
        acc[d4 * 4 + 1] = fmaf(pv[u], w.y, acc[d4 * 4 + 1]);
        acc[d4 * 4 + 2] = fmaf(pv[u], w.z, acc[d4 * 4 + 2]);
        acc[d4 * 4 + 3] = fmaf(pv[u], w.w, acc[d4 * 4 + 3]);
      }
    }
  }
  float* o = P1 + r * 64;
#pragma unroll
  for (int d4 = 0; d4 < 16; ++d4)
    *(float4*)(o + d4 * 4) =
        make_float4(acc[d4 * 4], acc[d4 * 4 + 1], acc[d4 * 4 + 2], acc[d4 * 4 + 3]);
}

// ---------------------------------------------------------------------------
// Fused group + MLP + maxpool. Weights/biases read directly from global with
// wave-uniform addresses (scalar-load path, L2-hot). Thread = (query, sample).
// ---------------------------------------------------------------------------
__global__ __launch_bounds__(256) void mlp_kernel(
    const float* __restrict__ xyz, const float* __restrict__ new_xyz,
    const int* __restrict__ ballidx, const float* __restrict__ P1,
    const float* __restrict__ W0, const float* __restrict__ b0,
    const float* __restrict__ W1, const float* __restrict__ b1,
    const float* __restrict__ W2, const float* __restrict__ b2,
    float* __restrict__ out_np) {
  const int t = threadIdx.x;
  const int item = blockIdx.x * 256 + t;
  const int k = item & 31;
  const int q = item >> 5;
  const int b = q >> 10;
  const int idx = ballidx[(size_t)q * 32 + k];
  const float nx = new_xyz[(size_t)q * 3];
  const float ny = new_xyz[(size_t)q * 3 + 1];
  const float nz = new_xyz[(size_t)q * 3 + 2];
  const float* p = xyz + ((size_t)b * NPTS + idx) * 3;
  const float dx = p[0] - nx, dy = p[1] - ny, dz = p[2] - nz;

  float h1[64];
  const float* p1r = P1 + ((size_t)b * NPTS + idx) * 64;
#pragma unroll
  for (int d4 = 0; d4 < 16; ++d4) {
    const float4 pv = *(const float4*)(p1r + d4 * 4);
    const float pe[4] = {pv.x, pv.y, pv.z, pv.w};
#pragma unroll
    for (int u = 0; u < 4; ++u) {
      const int d = d4 * 4 + u;
      const float v = pe[u] + dx * W0[d] + dy * W0[64 + d] + dz * W0[128 + d] + b0[d];
      h1[d] = fmaxf(v, 0.0f);
    }
  }

  float h2[64];
#pragma unroll
  for (int j4 = 0; j4 < 16; ++j4) {
    const float4 bb = *(const float4*)(&b1[j4 * 4]);
    h2[j4 * 4 + 0] = bb.x; h2[j4 * 4 + 1] = bb.y;
    h2[j4 * 4 + 2] = bb.z; h2[j4 * 4 + 3] = bb.w;
  }
#pragma unroll
  for (int c = 0; c < 64; ++c) {
    const float hc = h1[c];
#pragma unroll
    for (int j4 = 0; j4 < 16; ++j4) {
      const float4 w = *(const float4*)(&W1[c * 64 + j4 * 4]);
      h2[j4 * 4 + 0] = fmaf(hc, w.x, h2[j4 * 4 + 0]);
      h2[j4 * 4 + 1] = fmaf(hc, w.y, h2[j4 * 4 + 1]);
      h2[j4 * 4 + 2] = fmaf(hc, w.z, h2[j4 * 4 + 2]);
      h2[j4 * 4 + 3] = fmaf(hc, w.w, h2[j4 * 4 + 3]);
    }
  }
#pragma unroll
  for (int j = 0; j < 64; ++j) h2[j] = fmaxf(h2[j], 0.0f);

  float* outq = out_np + (size_t)q * 128;
  for (int jb = 0; jb < 4; ++jb) {
    float acc[32];
#pragma unroll
    for (int j8 = 0; j8 < 8; ++j8) {
      const float4 bb = *(const float4*)(&b2[jb * 32 + j8 * 4]);
      acc[j8 * 4 + 0] = bb.x; acc[j8 * 4 + 1] = bb.y;
      acc[j8 * 4 + 2] = bb.z; acc[j8 * 4 + 3] = bb.w;
    }
#pragma unroll
    for (int c = 0; c < 64; ++c) {
      const float hc = h2[c];
#pragma unroll
      for (int j8 = 0; j8 < 8; ++j8) {
        const float4 w = *(const float4*)(&W2[c * 128 + jb * 32 + j8 * 4]);
        acc[j8 * 4 + 0] = fmaf(hc, w.x, acc[j8 * 4 + 0]);
        acc[j8 * 4 + 1] = fmaf(hc, w.y, acc[j8 * 4 + 1]);
        acc[j8 * 4 + 2] = fmaf(hc, w.z, acc[j8 * 4 + 2]);
        acc[j8 * 4 + 3] = fmaf(hc, w.w, acc[j8 * 4 + 3]);
      }
    }
#pragma unroll
    for (int j = 0; j < 32; ++j) acc[j] = fmaxf(acc[j], 0.0f);
#pragma unroll
    for (int msk = 16; msk >= 1; msk >>= 1) {
#pragma unroll
      for (int j = 0; j < 32; ++j) acc[j] = fmaxf(acc[j], __shfl_xor(acc[j], msk, 64));
    }
    if (k == 0) {
#pragma unroll
      for (int j8 = 0; j8 < 8; ++j8)
        *(float4*)(outq + jb * 32 + j8 * 4) =
            make_float4(acc[j8 * 4 + 0], acc[j8 * 4 + 1], acc[j8 * 4 + 2], acc[j8 * 4 + 3]);
    }
  }
}

extern "C" void kernel_launch(void* const* d_in, const int* in_sizes, int n_in,
                              void* d_out, int out_size, void* d_ws, size_t ws_size,
                              hipStream_t stream) {
  const float* xyz = (const float*)d_in[0];
  const float* pts = (const float*)d_in[1];
  const float* W0  = (const float*)d_in[2];
  const float* b0  = (const float*)d_in[3];
  const float* W1  = (const float*)d_in[4];
  const float* b1  = (const float*)d_in[5];
  const float* W2  = (const float*)d_in[6];
  const float* b2  = (const float*)d_in[7];

  float* out      = (float*)d_out;
  float* out_xyz  = out;                       // [16,1024,3]
  float* out_np   = out + 16 * 1024 * 3;       // [16,1024,128]
  float* out_idx  = out_np + 16 * 1024 * 128;  // [16,1024,32] as float values

  int*   ballidx = (int*)d_ws;                               // 2 MB
  float* P1      = (float*)((char*)d_ws + (2u << 20));       // 16 MB

  fps_kernel<<<NB, 512, 0, stream>>>(xyz, out_xyz);
  p1_kernel<<<256, 256, 0, stream>>>(pts, W0, P1);
  ballq_kernel<<<4096, 256, 0, stream>>>(xyz, out_xyz, ballidx, out_idx);
  mlp_kernel<<<2048, 256, 0, stream>>>(xyz, out_xyz, ballidx, P1,
                                       W0, b0, W1, b1, W2, b2, out_np);
}